// Round 1
// baseline (1378.384 us; speedup 1.0000x reference)
//
#include <hip/hip_runtime.h>
#include <stdint.h>

#define RELS 8
#define F 256
#define KDIM 2304   // 8*256 stacked relations + 256 root/self columns

typedef __attribute__((ext_vector_type(8))) short short8;
typedef __attribute__((ext_vector_type(4))) float f32x4;

__device__ __forceinline__ unsigned short f2bf(float f) {
  union { float f; unsigned int u; } v; v.f = f;
  unsigned int u = v.u;
  if ((u & 0x7f800000u) == 0x7f800000u) return (unsigned short)(u >> 16); // inf/nan passthrough
  return (unsigned short)((u + 0x7fffu + ((u >> 16) & 1u)) >> 16);        // RNE
}
__device__ __forceinline__ float bf2f(unsigned short b) {
  union { unsigned int u; float f; } v; v.u = ((unsigned int)b) << 16; return v.f;
}

// ---- weight convert + transpose:  Wt[n][k] = bf16( k<2048 ? W[k][n] : root[k-2048][n] )
__global__ void k_wt(const float* __restrict__ W, const float* __restrict__ root,
                     unsigned short* __restrict__ Wt, int Ncols) {
  int tid = blockIdx.x * blockDim.x + threadIdx.x;
  int total = Ncols * KDIM;
  if (tid >= total) return;
  int n = tid / KDIM, k = tid - n * KDIM;
  float v = (k < 2048) ? W[(size_t)k * Ncols + n] : root[(size_t)(k - 2048) * Ncols + n];
  Wt[(size_t)n * KDIM + k] = f2bf(v);
}

// ---- CSR build ----
__global__ void k_count(const int* __restrict__ ei, const int* __restrict__ et,
                        int* __restrict__ cnt, int E) {
  int e = blockIdx.x * blockDim.x + threadIdx.x;
  if (e >= E) return;
  int bin = ei[E + e] * RELS + et[e];
  atomicAdd(&cnt[bin], 1);
}

__global__ void k_scan(const int* __restrict__ cnt, int* __restrict__ start, int nb) {
  __shared__ int sums[1024];
  int t = threadIdx.x;
  int chunk = (nb + 1023) >> 10;
  int lo = t * chunk, hi = lo + chunk; if (hi > nb) hi = nb; if (lo > nb) lo = nb;
  int s = 0;
  for (int i = lo; i < hi; i++) s += cnt[i];
  sums[t] = s;
  __syncthreads();
  for (int d = 1; d < 1024; d <<= 1) {
    int v = (t >= d) ? sums[t - d] : 0;
    __syncthreads();
    sums[t] += v;
    __syncthreads();
  }
  int run = (t > 0) ? sums[t - 1] : 0;
  for (int i = lo; i < hi; i++) { start[i] = run; run += cnt[i]; }
  if (t == 1023) start[nb] = sums[1023];
}

__global__ void k_scatter(const int* __restrict__ ei, const int* __restrict__ et,
                          const int* __restrict__ start, int* __restrict__ cur,
                          int* __restrict__ ssrc, int E) {
  int e = blockIdx.x * blockDim.x + threadIdx.x;
  if (e >= E) return;
  int bin = ei[E + e] * RELS + et[e];
  int p = atomicAdd(&cur[bin], 1);
  ssrc[start[bin] + p] = ei[e];
}

// ---- aggregation: one wave per (dst, rel) bin; 64 lanes cover 256 features ----
__global__ void k_agg_f32(const float* __restrict__ x, const int* __restrict__ start,
                          const int* __restrict__ ssrc, unsigned short* __restrict__ A,
                          int nbins) {
  int w = blockIdx.x * 4 + (threadIdx.x >> 6);
  int lane = threadIdx.x & 63;
  if (w >= nbins) return;
  int s0 = start[w], s1 = start[w + 1];
  int deg = s1 - s0;
  float scale = 1.0f / (float)(deg > 1 ? deg : 1);
  float a0 = 0.f, a1 = 0.f, a2 = 0.f, a3 = 0.f;
  for (int e = s0; e < s1; e++) {
    int s = ssrc[e];
    const float4 v = *(const float4*)&x[(size_t)s * F + lane * 4];
    a0 += v.x; a1 += v.y; a2 += v.z; a3 += v.w;
  }
  int n = w >> 3, r = w & 7;
  ushort4 o;
  o.x = f2bf(a0 * scale); o.y = f2bf(a1 * scale);
  o.z = f2bf(a2 * scale); o.w = f2bf(a3 * scale);
  *(ushort4*)&A[(size_t)n * KDIM + r * F + lane * 4] = o;
}

__global__ void k_agg_bf16(const unsigned short* __restrict__ h, const int* __restrict__ start,
                           const int* __restrict__ ssrc, unsigned short* __restrict__ A,
                           int nbins) {
  int w = blockIdx.x * 4 + (threadIdx.x >> 6);
  int lane = threadIdx.x & 63;
  if (w >= nbins) return;
  int s0 = start[w], s1 = start[w + 1];
  int deg = s1 - s0;
  float scale = 1.0f / (float)(deg > 1 ? deg : 1);
  float a0 = 0.f, a1 = 0.f, a2 = 0.f, a3 = 0.f;
  for (int e = s0; e < s1; e++) {
    int s = ssrc[e];
    const ushort4 v = *(const ushort4*)&h[(size_t)s * F + lane * 4];
    a0 += bf2f(v.x); a1 += bf2f(v.y); a2 += bf2f(v.z); a3 += bf2f(v.w);
  }
  int n = w >> 3, r = w & 7;
  ushort4 o;
  o.x = f2bf(a0 * scale); o.y = f2bf(a1 * scale);
  o.z = f2bf(a2 * scale); o.w = f2bf(a3 * scale);
  *(ushort4*)&A[(size_t)n * KDIM + r * F + lane * 4] = o;
}

// ---- copy self features into the last 256 K-columns of A ----
__global__ void k_copy_x(const float* __restrict__ x, unsigned short* __restrict__ A, int N) {
  int tid = blockIdx.x * blockDim.x + threadIdx.x;
  int n = tid >> 6, q = tid & 63;
  if (n >= N) return;
  const float4 v = *(const float4*)&x[(size_t)n * F + q * 4];
  ushort4 o;
  o.x = f2bf(v.x); o.y = f2bf(v.y); o.z = f2bf(v.z); o.w = f2bf(v.w);
  *(ushort4*)&A[(size_t)n * KDIM + 2048 + q * 4] = o;
}

__global__ void k_copy_h(const unsigned short* __restrict__ h, unsigned short* __restrict__ A, int N) {
  int tid = blockIdx.x * blockDim.x + threadIdx.x;
  int n = tid >> 6, q = tid & 63;
  if (n >= N) return;
  const ushort4 v = *(const ushort4*)&h[(size_t)n * F + q * 4];
  *(ushort4*)&A[(size_t)n * KDIM + 2048 + q * 4] = v;
}

// ---- 128x128 bf16 MFMA GEMM:  out[M,Nld] = A[M,KDIM] @ Bt[Nld,KDIM]^T + bias ----
template<bool RELU, bool OUTBF16>
__global__ __launch_bounds__(256) void k_gemm(
    const unsigned short* __restrict__ Ag, const unsigned short* __restrict__ Bg,
    const float* __restrict__ bias, void* __restrict__ outp,
    int Nld, int Mreal) {
  __shared__ unsigned short As[128 * 32];
  __shared__ unsigned short Bs[128 * 32];
  const int t = threadIdx.x;
  const int m0 = blockIdx.x * 128;
  const int n0 = blockIdx.y * 128;
  const int lane = t & 63, wid = t >> 6;
  const int wm = (wid >> 1) * 64, wn = (wid & 1) * 64;
  const int c15 = lane & 15, quad = lane >> 4;

  f32x4 acc[4][4];
#pragma unroll
  for (int i = 0; i < 4; i++)
#pragma unroll
    for (int j = 0; j < 4; j++) acc[i][j] = (f32x4)0.f;

  for (int kt = 0; kt < KDIM; kt += 32) {
#pragma unroll
    for (int i = 0; i < 2; i++) {
      int flat = i * 2048 + t * 8;
      int row = flat >> 5, cc = flat & 31;
      *(int4*)&As[flat] = *(const int4*)&Ag[(size_t)(m0 + row) * KDIM + kt + cc];
      *(int4*)&Bs[flat] = *(const int4*)&Bg[(size_t)(n0 + row) * KDIM + kt + cc];
    }
    __syncthreads();
    short8 af[4], bf[4];
#pragma unroll
    for (int mi = 0; mi < 4; mi++)
      af[mi] = *(const short8*)&As[(wm + mi * 16 + c15) * 32 + quad * 8];
#pragma unroll
    for (int ni = 0; ni < 4; ni++)
      bf[ni] = *(const short8*)&Bs[(wn + ni * 16 + c15) * 32 + quad * 8];
#pragma unroll
    for (int mi = 0; mi < 4; mi++)
#pragma unroll
      for (int ni = 0; ni < 4; ni++)
        acc[mi][ni] = __builtin_amdgcn_mfma_f32_16x16x32_bf16(af[mi], bf[ni], acc[mi][ni], 0, 0, 0);
    __syncthreads();
  }

#pragma unroll
  for (int mi = 0; mi < 4; mi++) {
#pragma unroll
    for (int ni = 0; ni < 4; ni++) {
      int n = n0 + wn + ni * 16 + c15;
      float bv = bias[n];
#pragma unroll
      for (int r = 0; r < 4; r++) {
        int m = m0 + wm + mi * 16 + quad * 4 + r;
        if (m < Mreal) {
          float v = acc[mi][ni][r] + bv;
          if (RELU) v = v > 0.f ? v : 0.f;
          if (OUTBF16) ((unsigned short*)outp)[(size_t)m * Nld + n] = f2bf(v);
          else         ((float*)outp)[(size_t)m * Nld + n] = v;
        }
      }
    }
  }
}

extern "C" void kernel_launch(void* const* d_in, const int* in_sizes, int n_in,
                              void* d_out, int out_size, void* d_ws, size_t ws_size,
                              hipStream_t stream) {
  const float* x     = (const float*)d_in[0];
  const int*   ei    = (const int*)d_in[1];   // [2, E]: src row then dst row
  const int*   et    = (const int*)d_in[2];   // [E]
  const float* W1    = (const float*)d_in[3]; // [8,256,256] == [2048,256]
  const float* root1 = (const float*)d_in[4]; // [256,256]
  const float* b1    = (const float*)d_in[5];
  const float* W2    = (const float*)d_in[6]; // [2048,128]
  const float* root2 = (const float*)d_in[7]; // [256,128]
  const float* b2    = (const float*)d_in[8];

  const int N = in_sizes[0] / F;              // 50000
  const int E = in_sizes[2];                  // 800000
  const int nbins = N * RELS;                 // 400000
  const int Mpad = ((N + 127) / 128) * 128;   // 50048

  char* base = (char*)d_ws;
  size_t off = 0;
  auto alloc = [&](size_t bytes) {
    void* r = base + off;
    off = (off + bytes + 511) & ~(size_t)511;
    return r;
  };
  unsigned short* Wt1  = (unsigned short*)alloc((size_t)256 * KDIM * 2);
  unsigned short* Wt2  = (unsigned short*)alloc((size_t)128 * KDIM * 2);
  int*            cnt  = (int*)alloc((size_t)nbins * 4);
  int*            strt = (int*)alloc((size_t)(nbins + 1) * 4);
  int*            ssrc = (int*)alloc((size_t)E * 4);
  unsigned short* A    = (unsigned short*)alloc((size_t)Mpad * KDIM * 2);
  unsigned short* h    = (unsigned short*)alloc((size_t)Mpad * F * 2);
  (void)ws_size; (void)n_in; (void)out_size;

  hipMemsetAsync(cnt, 0, (size_t)nbins * 4, stream);
  k_wt<<<(256 * KDIM + 255) / 256, 256, 0, stream>>>(W1, root1, Wt1, 256);
  k_wt<<<(128 * KDIM + 255) / 256, 256, 0, stream>>>(W2, root2, Wt2, 128);
  k_count<<<(E + 255) / 256, 256, 0, stream>>>(ei, et, cnt, E);
  k_scan<<<1, 1024, 0, stream>>>(cnt, strt, nbins);
  hipMemsetAsync(cnt, 0, (size_t)nbins * 4, stream);  // reuse as cursor
  k_scatter<<<(E + 255) / 256, 256, 0, stream>>>(ei, et, strt, cnt, ssrc, E);

  // Layer 1
  k_agg_f32<<<(nbins + 3) / 4, 256, 0, stream>>>(x, strt, ssrc, A, nbins);
  k_copy_x<<<(N * 64 + 255) / 256, 256, 0, stream>>>(x, A, N);
  k_gemm<true, true><<<dim3(Mpad / 128, 2), 256, 0, stream>>>(A, Wt1, b1, h, 256, N);

  // Layer 2
  k_agg_bf16<<<(nbins + 3) / 4, 256, 0, stream>>>(h, strt, ssrc, A, nbins);
  k_copy_h<<<(N * 64 + 255) / 256, 256, 0, stream>>>(h, A, N);
  k_gemm<false, false><<<dim3(Mpad / 128, 1), 256, 0, stream>>>(A, Wt2, b2, d_out, 128, N);
}

// Round 2
// 744.480 us; speedup vs baseline: 1.8515x; 1.8515x over previous
//
#include <hip/hip_runtime.h>
#include <stdint.h>

#define RELS 8
#define F 256
#define KDIM 2304   // 8*256 stacked relations + 256 root/self columns
#define SCAN_CHUNK 1024  // bins per scan1 block (256 threads x 4)

typedef __attribute__((ext_vector_type(8))) short short8;
typedef __attribute__((ext_vector_type(4))) float f32x4;

__device__ __forceinline__ unsigned short f2bf(float f) {
  union { float f; unsigned int u; } v; v.f = f;
  unsigned int u = v.u;
  if ((u & 0x7f800000u) == 0x7f800000u) return (unsigned short)(u >> 16); // inf/nan passthrough
  return (unsigned short)((u + 0x7fffu + ((u >> 16) & 1u)) >> 16);        // RNE
}
__device__ __forceinline__ float bf2f(unsigned short b) {
  union { unsigned int u; float f; } v; v.u = ((unsigned int)b) << 16; return v.f;
}

// ---- weight convert + transpose:  Wt[n][k] = bf16( k<2048 ? W[k][n] : root[k-2048][n] )
__global__ void k_wt(const float* __restrict__ W, const float* __restrict__ root,
                     unsigned short* __restrict__ Wt, int Ncols) {
  int tid = blockIdx.x * blockDim.x + threadIdx.x;
  int total = Ncols * KDIM;
  if (tid >= total) return;
  int n = tid / KDIM, k = tid - n * KDIM;
  float v = (k < 2048) ? W[(size_t)k * Ncols + n] : root[(size_t)(k - 2048) * Ncols + n];
  Wt[(size_t)n * KDIM + k] = f2bf(v);
}

// ---- CSR build ----
__global__ void k_count(const int* __restrict__ ei, const int* __restrict__ et,
                        int* __restrict__ cnt, int E) {
  int e = blockIdx.x * blockDim.x + threadIdx.x;
  if (e >= E) return;
  int bin = ei[E + e] * RELS + et[e];
  atomicAdd(&cnt[bin], 1);
}

// ---- 3-phase hierarchical exclusive scan over nb bins ----
__global__ void k_scan1(const int* __restrict__ cnt, int* __restrict__ start,
                        int* __restrict__ bsum, int nb) {
  __shared__ int tsum[256];
  const int t = threadIdx.x;
  const int idx = blockIdx.x * SCAN_CHUNK + t * 4;
  int v[4]; int s = 0;
#pragma unroll
  for (int i = 0; i < 4; i++) { v[i] = (idx + i < nb) ? cnt[idx + i] : 0; s += v[i]; }
  tsum[t] = s;
  __syncthreads();
  for (int d = 1; d < 256; d <<= 1) {
    int a = (t >= d) ? tsum[t - d] : 0;
    __syncthreads();
    tsum[t] += a;
    __syncthreads();
  }
  int ex = (t > 0) ? tsum[t - 1] : 0;
#pragma unroll
  for (int i = 0; i < 4; i++) { if (idx + i < nb) start[idx + i] = ex; ex += v[i]; }
  if (t == 255) bsum[blockIdx.x] = tsum[255];
}

__global__ void k_scan2(int* __restrict__ bsum, int nblocks) {
  __shared__ int sh[1024];
  const int t = threadIdx.x;
  sh[t] = (t < nblocks) ? bsum[t] : 0;
  __syncthreads();
  for (int d = 1; d < 1024; d <<= 1) {
    int a = (t >= d) ? sh[t - d] : 0;
    __syncthreads();
    sh[t] += a;
    __syncthreads();
  }
  if (t < nblocks) bsum[t] = (t > 0) ? sh[t - 1] : 0;   // exclusive
  if (t == 1023) bsum[nblocks] = sh[1023];              // grand total
}

__global__ void k_scan3(int* __restrict__ start, const int* __restrict__ bsum,
                        int nb, int nblocks) {
  int i = blockIdx.x * blockDim.x + threadIdx.x;
  if (i < nb) start[i] += bsum[i >> 10];  // SCAN_CHUNK == 1024
  if (i == 0) start[nb] = bsum[nblocks];
}

__global__ void k_scatter(const int* __restrict__ ei, const int* __restrict__ et,
                          const int* __restrict__ start, int* __restrict__ cur,
                          int* __restrict__ ssrc, int E) {
  int e = blockIdx.x * blockDim.x + threadIdx.x;
  if (e >= E) return;
  int bin = ei[E + e] * RELS + et[e];
  int p = atomicAdd(&cur[bin], 1);
  ssrc[start[bin] + p] = ei[e];
}

// ---- aggregation: one wave per (dst, rel) bin; 64 lanes cover 256 features ----
__global__ void k_agg_f32(const float* __restrict__ x, const int* __restrict__ start,
                          const int* __restrict__ ssrc, unsigned short* __restrict__ A,
                          int nbins) {
  int w = blockIdx.x * 4 + (threadIdx.x >> 6);
  int lane = threadIdx.x & 63;
  if (w >= nbins) return;
  int s0 = start[w], s1 = start[w + 1];
  int deg = s1 - s0;
  float scale = 1.0f / (float)(deg > 1 ? deg : 1);
  float a0 = 0.f, a1 = 0.f, a2 = 0.f, a3 = 0.f;
  for (int e = s0; e < s1; e++) {
    int s = ssrc[e];
    const float4 v = *(const float4*)&x[(size_t)s * F + lane * 4];
    a0 += v.x; a1 += v.y; a2 += v.z; a3 += v.w;
  }
  int n = w >> 3, r = w & 7;
  ushort4 o;
  o.x = f2bf(a0 * scale); o.y = f2bf(a1 * scale);
  o.z = f2bf(a2 * scale); o.w = f2bf(a3 * scale);
  *(ushort4*)&A[(size_t)n * KDIM + r * F + lane * 4] = o;
}

__global__ void k_agg_bf16(const unsigned short* __restrict__ h, const int* __restrict__ start,
                           const int* __restrict__ ssrc, unsigned short* __restrict__ A,
                           int nbins) {
  int w = blockIdx.x * 4 + (threadIdx.x >> 6);
  int lane = threadIdx.x & 63;
  if (w >= nbins) return;
  int s0 = start[w], s1 = start[w + 1];
  int deg = s1 - s0;
  float scale = 1.0f / (float)(deg > 1 ? deg : 1);
  float a0 = 0.f, a1 = 0.f, a2 = 0.f, a3 = 0.f;
  for (int e = s0; e < s1; e++) {
    int s = ssrc[e];
    const ushort4 v = *(const ushort4*)&h[(size_t)s * F + lane * 4];
    a0 += bf2f(v.x); a1 += bf2f(v.y); a2 += bf2f(v.z); a3 += bf2f(v.w);
  }
  int n = w >> 3, r = w & 7;
  ushort4 o;
  o.x = f2bf(a0 * scale); o.y = f2bf(a1 * scale);
  o.z = f2bf(a2 * scale); o.w = f2bf(a3 * scale);
  *(ushort4*)&A[(size_t)n * KDIM + r * F + lane * 4] = o;
}

// ---- copy self features into the last 256 K-columns of A ----
__global__ void k_copy_x(const float* __restrict__ x, unsigned short* __restrict__ A, int N) {
  int tid = blockIdx.x * blockDim.x + threadIdx.x;
  int n = tid >> 6, q = tid & 63;
  if (n >= N) return;
  const float4 v = *(const float4*)&x[(size_t)n * F + q * 4];
  ushort4 o;
  o.x = f2bf(v.x); o.y = f2bf(v.y); o.z = f2bf(v.z); o.w = f2bf(v.w);
  *(ushort4*)&A[(size_t)n * KDIM + 2048 + q * 4] = o;
}

__global__ void k_copy_h(const unsigned short* __restrict__ h, unsigned short* __restrict__ A, int N) {
  int tid = blockIdx.x * blockDim.x + threadIdx.x;
  int n = tid >> 6, q = tid & 63;
  if (n >= N) return;
  const ushort4 v = *(const ushort4*)&h[(size_t)n * F + q * 4];
  *(ushort4*)&A[(size_t)n * KDIM + 2048 + q * 4] = v;
}

// ---- 128x128 bf16 MFMA GEMM:  out[M,Nld] = A[M,KDIM] @ Bt[Nld,KDIM]^T + bias ----
template<bool RELU, bool OUTBF16>
__global__ __launch_bounds__(256) void k_gemm(
    const unsigned short* __restrict__ Ag, const unsigned short* __restrict__ Bg,
    const float* __restrict__ bias, void* __restrict__ outp,
    int Nld, int Mreal) {
  __shared__ unsigned short As[128 * 32];
  __shared__ unsigned short Bs[128 * 32];
  const int t = threadIdx.x;
  const int m0 = blockIdx.x * 128;
  const int n0 = blockIdx.y * 128;
  const int lane = t & 63, wid = t >> 6;
  const int wm = (wid >> 1) * 64, wn = (wid & 1) * 64;
  const int c15 = lane & 15, quad = lane >> 4;

  f32x4 acc[4][4];
#pragma unroll
  for (int i = 0; i < 4; i++)
#pragma unroll
    for (int j = 0; j < 4; j++) acc[i][j] = (f32x4)0.f;

  for (int kt = 0; kt < KDIM; kt += 32) {
#pragma unroll
    for (int i = 0; i < 2; i++) {
      int flat = i * 2048 + t * 8;
      int row = flat >> 5, cc = flat & 31;
      *(int4*)&As[flat] = *(const int4*)&Ag[(size_t)(m0 + row) * KDIM + kt + cc];
      *(int4*)&Bs[flat] = *(const int4*)&Bg[(size_t)(n0 + row) * KDIM + kt + cc];
    }
    __syncthreads();
    short8 af[4], bf[4];
#pragma unroll
    for (int mi = 0; mi < 4; mi++)
      af[mi] = *(const short8*)&As[(wm + mi * 16 + c15) * 32 + quad * 8];
#pragma unroll
    for (int ni = 0; ni < 4; ni++)
      bf[ni] = *(const short8*)&Bs[(wn + ni * 16 + c15) * 32 + quad * 8];
#pragma unroll
    for (int mi = 0; mi < 4; mi++)
#pragma unroll
      for (int ni = 0; ni < 4; ni++)
        acc[mi][ni] = __builtin_amdgcn_mfma_f32_16x16x32_bf16(af[mi], bf[ni], acc[mi][ni], 0, 0, 0);
    __syncthreads();
  }

#pragma unroll
  for (int mi = 0; mi < 4; mi++) {
#pragma unroll
    for (int ni = 0; ni < 4; ni++) {
      int n = n0 + wn + ni * 16 + c15;
      float bv = bias[n];
#pragma unroll
      for (int r = 0; r < 4; r++) {
        int m = m0 + wm + mi * 16 + quad * 4 + r;
        if (m < Mreal) {
          float v = acc[mi][ni][r] + bv;
          if (RELU) v = v > 0.f ? v : 0.f;
          if (OUTBF16) ((unsigned short*)outp)[(size_t)m * Nld + n] = f2bf(v);
          else         ((float*)outp)[(size_t)m * Nld + n] = v;
        }
      }
    }
  }
}

extern "C" void kernel_launch(void* const* d_in, const int* in_sizes, int n_in,
                              void* d_out, int out_size, void* d_ws, size_t ws_size,
                              hipStream_t stream) {
  const float* x     = (const float*)d_in[0];
  const int*   ei    = (const int*)d_in[1];   // [2, E]: src row then dst row
  const int*   et    = (const int*)d_in[2];   // [E]
  const float* W1    = (const float*)d_in[3]; // [8,256,256] == [2048,256]
  const float* root1 = (const float*)d_in[4]; // [256,256]
  const float* b1    = (const float*)d_in[5];
  const float* W2    = (const float*)d_in[6]; // [2048,128]
  const float* root2 = (const float*)d_in[7]; // [256,128]
  const float* b2    = (const float*)d_in[8];

  const int N = in_sizes[0] / F;              // 50000
  const int E = in_sizes[2];                  // 800000
  const int nbins = N * RELS;                 // 400000
  const int Mpad = ((N + 127) / 128) * 128;   // 50048
  const int nsb = (nbins + SCAN_CHUNK - 1) / SCAN_CHUNK;  // scan1 blocks (391)

  char* base = (char*)d_ws;
  size_t off = 0;
  auto alloc = [&](size_t bytes) {
    void* r = base + off;
    off = (off + bytes + 511) & ~(size_t)511;
    return r;
  };
  unsigned short* Wt1  = (unsigned short*)alloc((size_t)256 * KDIM * 2);
  unsigned short* Wt2  = (unsigned short*)alloc((size_t)128 * KDIM * 2);
  int*            cnt  = (int*)alloc((size_t)nbins * 4);
  int*            strt = (int*)alloc((size_t)(nbins + 1) * 4);
  int*            bsum = (int*)alloc((size_t)(nsb + 1) * 4);
  int*            ssrc = (int*)alloc((size_t)E * 4);
  unsigned short* A    = (unsigned short*)alloc((size_t)Mpad * KDIM * 2);
  unsigned short* h    = (unsigned short*)alloc((size_t)Mpad * F * 2);
  (void)ws_size; (void)n_in; (void)out_size;

  hipMemsetAsync(cnt, 0, (size_t)nbins * 4, stream);
  k_wt<<<(256 * KDIM + 255) / 256, 256, 0, stream>>>(W1, root1, Wt1, 256);
  k_wt<<<(128 * KDIM + 255) / 256, 256, 0, stream>>>(W2, root2, Wt2, 128);
  k_count<<<(E + 255) / 256, 256, 0, stream>>>(ei, et, cnt, E);
  k_scan1<<<nsb, 256, 0, stream>>>(cnt, strt, bsum, nbins);
  k_scan2<<<1, 1024, 0, stream>>>(bsum, nsb);
  k_scan3<<<(nbins + 255) / 256, 256, 0, stream>>>(strt, bsum, nbins, nsb);
  hipMemsetAsync(cnt, 0, (size_t)nbins * 4, stream);  // reuse as cursor
  k_scatter<<<(E + 255) / 256, 256, 0, stream>>>(ei, et, strt, cnt, ssrc, E);

  // Layer 1
  k_agg_f32<<<(nbins + 3) / 4, 256, 0, stream>>>(x, strt, ssrc, A, nbins);
  k_copy_x<<<(N * 64 + 255) / 256, 256, 0, stream>>>(x, A, N);
  k_gemm<true, true><<<dim3(Mpad / 128, 2), 256, 0, stream>>>(A, Wt1, b1, h, 256, N);

  // Layer 2
  k_agg_bf16<<<(nbins + 3) / 4, 256, 0, stream>>>(h, strt, ssrc, A, nbins);
  k_copy_h<<<(N * 64 + 255) / 256, 256, 0, stream>>>(h, A, N);
  k_gemm<false, false><<<dim3(Mpad / 128, 1), 256, 0, stream>>>(A, Wt2, b2, d_out, 128, N);
}

// Round 3
// 669.015 us; speedup vs baseline: 2.0603x; 1.1128x over previous
//
#include <hip/hip_runtime.h>
#include <stdint.h>

#define RELS 8
#define F 256
#define KDIM 2304   // 8*256 stacked relations + 256 root/self columns
#define SCAN_CHUNK 1024  // bins per scan1 block (256 threads x 4)

typedef __attribute__((ext_vector_type(8))) short short8;
typedef __attribute__((ext_vector_type(4))) float f32x4;

__device__ __forceinline__ unsigned short f2bf(float f) {
  union { float f; unsigned int u; } v; v.f = f;
  unsigned int u = v.u;
  if ((u & 0x7f800000u) == 0x7f800000u) return (unsigned short)(u >> 16); // inf/nan passthrough
  return (unsigned short)((u + 0x7fffu + ((u >> 16) & 1u)) >> 16);        // RNE
}
__device__ __forceinline__ float bf2f(unsigned short b) {
  union { unsigned int u; float f; } v; v.u = ((unsigned int)b) << 16; return v.f;
}

// async 16B global -> LDS (wave-uniform base + lane*16; our layouts satisfy this)
#define GLOAD_LDS16(g, l)                                              \
  __builtin_amdgcn_global_load_lds(                                    \
      (const __attribute__((address_space(1))) void*)(g),              \
      (__attribute__((address_space(3))) void*)(l), 16, 0, 0)

// ---- weight convert + transpose:  Wt[n][k] = bf16( k<2048 ? W[k][n] : root[k-2048][n] )
__global__ void k_wt(const float* __restrict__ W, const float* __restrict__ root,
                     unsigned short* __restrict__ Wt, int Ncols) {
  int tid = blockIdx.x * blockDim.x + threadIdx.x;
  int total = Ncols * KDIM;
  if (tid >= total) return;
  int n = tid / KDIM, k = tid - n * KDIM;
  float v = (k < 2048) ? W[(size_t)k * Ncols + n] : root[(size_t)(k - 2048) * Ncols + n];
  Wt[(size_t)n * KDIM + k] = f2bf(v);
}

// ---- CSR build ----
__global__ void k_count(const int* __restrict__ ei, const int* __restrict__ et,
                        int* __restrict__ cnt, int E) {
  int e = blockIdx.x * blockDim.x + threadIdx.x;
  if (e >= E) return;
  int bin = ei[E + e] * RELS + et[e];
  atomicAdd(&cnt[bin], 1);
}

// ---- 3-phase hierarchical exclusive scan over nb bins ----
__global__ void k_scan1(const int* __restrict__ cnt, int* __restrict__ start,
                        int* __restrict__ bsum, int nb) {
  __shared__ int tsum[256];
  const int t = threadIdx.x;
  const int idx = blockIdx.x * SCAN_CHUNK + t * 4;
  int v[4]; int s = 0;
#pragma unroll
  for (int i = 0; i < 4; i++) { v[i] = (idx + i < nb) ? cnt[idx + i] : 0; s += v[i]; }
  tsum[t] = s;
  __syncthreads();
  for (int d = 1; d < 256; d <<= 1) {
    int a = (t >= d) ? tsum[t - d] : 0;
    __syncthreads();
    tsum[t] += a;
    __syncthreads();
  }
  int ex = (t > 0) ? tsum[t - 1] : 0;
#pragma unroll
  for (int i = 0; i < 4; i++) { if (idx + i < nb) start[idx + i] = ex; ex += v[i]; }
  if (t == 255) bsum[blockIdx.x] = tsum[255];
}

__global__ void k_scan2(int* __restrict__ bsum, int nblocks) {
  __shared__ int sh[1024];
  const int t = threadIdx.x;
  sh[t] = (t < nblocks) ? bsum[t] : 0;
  __syncthreads();
  for (int d = 1; d < 1024; d <<= 1) {
    int a = (t >= d) ? sh[t - d] : 0;
    __syncthreads();
    sh[t] += a;
    __syncthreads();
  }
  if (t < nblocks) bsum[t] = (t > 0) ? sh[t - 1] : 0;   // exclusive
  if (t == 1023) bsum[nblocks] = sh[1023];              // grand total
}

__global__ void k_scan3(int* __restrict__ start, const int* __restrict__ bsum,
                        int nb, int nblocks) {
  int i = blockIdx.x * blockDim.x + threadIdx.x;
  if (i < nb) start[i] += bsum[i >> 10];  // SCAN_CHUNK == 1024
  if (i == 0) start[nb] = bsum[nblocks];
}

__global__ void k_scatter(const int* __restrict__ ei, const int* __restrict__ et,
                          const int* __restrict__ start, int* __restrict__ cur,
                          int* __restrict__ ssrc, int E) {
  int e = blockIdx.x * blockDim.x + threadIdx.x;
  if (e >= E) return;
  int bin = ei[E + e] * RELS + et[e];
  int p = atomicAdd(&cur[bin], 1);
  ssrc[start[bin] + p] = ei[e];
}

// ---- aggregation: one wave per (dst, rel) bin; 64 lanes cover 256 features ----
// src rows are bf16 with row stride sstride (elements).
__global__ void k_agg(const unsigned short* __restrict__ src, int sstride,
                      const int* __restrict__ start, const int* __restrict__ ssrc,
                      unsigned short* __restrict__ A, int nbins) {
  int w = blockIdx.x * 4 + (threadIdx.x >> 6);
  int lane = threadIdx.x & 63;
  if (w >= nbins) return;
  int s0 = start[w], s1 = start[w + 1];
  int deg = s1 - s0;
  float scale = 1.0f / (float)(deg > 1 ? deg : 1);
  float a0 = 0.f, a1 = 0.f, a2 = 0.f, a3 = 0.f;
  for (int e = s0; e < s1; e++) {
    int s = ssrc[e];
    const ushort4 v = *(const ushort4*)&src[(size_t)s * sstride + lane * 4];
    a0 += bf2f(v.x); a1 += bf2f(v.y); a2 += bf2f(v.z); a3 += bf2f(v.w);
  }
  int n = w >> 3, r = w & 7;
  ushort4 o;
  o.x = f2bf(a0 * scale); o.y = f2bf(a1 * scale);
  o.z = f2bf(a2 * scale); o.w = f2bf(a3 * scale);
  *(ushort4*)&A[(size_t)n * KDIM + r * F + lane * 4] = o;
}

// ---- copy self features into the last 256 K-columns of A ----
__global__ void k_copy_x(const float* __restrict__ x, unsigned short* __restrict__ A, int N) {
  int tid = blockIdx.x * blockDim.x + threadIdx.x;
  int n = tid >> 6, q = tid & 63;
  if (n >= N) return;
  const float4 v = *(const float4*)&x[(size_t)n * F + q * 4];
  ushort4 o;
  o.x = f2bf(v.x); o.y = f2bf(v.y); o.z = f2bf(v.z); o.w = f2bf(v.w);
  *(ushort4*)&A[(size_t)n * KDIM + 2048 + q * 4] = o;
}

__global__ void k_copy_h(const unsigned short* __restrict__ h, unsigned short* __restrict__ A, int N) {
  int tid = blockIdx.x * blockDim.x + threadIdx.x;
  int n = tid >> 6, q = tid & 63;
  if (n >= N) return;
  const ushort4 v = *(const ushort4*)&h[(size_t)n * F + q * 4];
  *(ushort4*)&A[(size_t)n * KDIM + 2048 + q * 4] = v;
}

// ---- 128x128 bf16 MFMA GEMM:  out[M,Nld] = A[M,KDIM] @ Bt[Nld,KDIM]^T + bias ----
// Staging via global_load_lds width=16 (m97 structure).
template<bool RELU, bool OUTBF16>
__global__ __launch_bounds__(256) void k_gemm(
    const unsigned short* __restrict__ Ag, const unsigned short* __restrict__ Bg,
    const float* __restrict__ bias, void* __restrict__ outp,
    int Nld, int Mreal) {
  __shared__ unsigned short As[128 * 32];
  __shared__ unsigned short Bs[128 * 32];
  const int t = threadIdx.x;
  const int m0 = blockIdx.x * 128;
  const int n0 = blockIdx.y * 128;
  const int lane = t & 63, wid = t >> 6;
  const int wm = (wid >> 1) * 64, wn = (wid & 1) * 64;
  const int c15 = lane & 15, quad = lane >> 4;

  f32x4 acc[4][4];
#pragma unroll
  for (int i = 0; i < 4; i++)
#pragma unroll
    for (int j = 0; j < 4; j++) acc[i][j] = (f32x4)0.f;

  // per-thread staging address components (flat = i*2048 + t*8 shorts == lane*16B pattern)
  const int flat0 = t * 8;
  const int row0 = flat0 >> 5, cc0 = flat0 & 31;   // chunk 0: rows 0..63
  const int flat1 = 2048 + t * 8;
  const int row1 = flat1 >> 5, cc1 = flat1 & 31;   // chunk 1: rows 64..127

  const unsigned short* Arow0 = &Ag[(size_t)(m0 + row0) * KDIM + cc0];
  const unsigned short* Arow1 = &Ag[(size_t)(m0 + row1) * KDIM + cc1];
  const unsigned short* Brow0 = &Bg[(size_t)(n0 + row0) * KDIM + cc0];
  const unsigned short* Brow1 = &Bg[(size_t)(n0 + row1) * KDIM + cc1];

  for (int kt = 0; kt < KDIM; kt += 32) {
    GLOAD_LDS16(Arow0 + kt, &As[flat0]);
    GLOAD_LDS16(Arow1 + kt, &As[flat1]);
    GLOAD_LDS16(Brow0 + kt, &Bs[flat0]);
    GLOAD_LDS16(Brow1 + kt, &Bs[flat1]);
    __syncthreads();
    short8 af[4], bf[4];
#pragma unroll
    for (int mi = 0; mi < 4; mi++)
      af[mi] = *(const short8*)&As[(wm + mi * 16 + c15) * 32 + quad * 8];
#pragma unroll
    for (int ni = 0; ni < 4; ni++)
      bf[ni] = *(const short8*)&Bs[(wn + ni * 16 + c15) * 32 + quad * 8];
#pragma unroll
    for (int mi = 0; mi < 4; mi++)
#pragma unroll
      for (int ni = 0; ni < 4; ni++)
        acc[mi][ni] = __builtin_amdgcn_mfma_f32_16x16x32_bf16(af[mi], bf[ni], acc[mi][ni], 0, 0, 0);
    __syncthreads();
  }

#pragma unroll
  for (int mi = 0; mi < 4; mi++) {
#pragma unroll
    for (int ni = 0; ni < 4; ni++) {
      int n = n0 + wn + ni * 16 + c15;
      float bv = bias[n];
#pragma unroll
      for (int r = 0; r < 4; r++) {
        int m = m0 + wm + mi * 16 + quad * 4 + r;
        if (m < Mreal) {
          float v = acc[mi][ni][r] + bv;
          if (RELU) v = v > 0.f ? v : 0.f;
          if (OUTBF16) ((unsigned short*)outp)[(size_t)m * Nld + n] = f2bf(v);
          else         ((float*)outp)[(size_t)m * Nld + n] = v;
        }
      }
    }
  }
}

extern "C" void kernel_launch(void* const* d_in, const int* in_sizes, int n_in,
                              void* d_out, int out_size, void* d_ws, size_t ws_size,
                              hipStream_t stream) {
  const float* x     = (const float*)d_in[0];
  const int*   ei    = (const int*)d_in[1];   // [2, E]: src row then dst row
  const int*   et    = (const int*)d_in[2];   // [E]
  const float* W1    = (const float*)d_in[3]; // [8,256,256] == [2048,256]
  const float* root1 = (const float*)d_in[4]; // [256,256]
  const float* b1    = (const float*)d_in[5];
  const float* W2    = (const float*)d_in[6]; // [2048,128]
  const float* root2 = (const float*)d_in[7]; // [256,128]
  const float* b2    = (const float*)d_in[8];

  const int N = in_sizes[0] / F;              // 50000
  const int E = in_sizes[2];                  // 800000
  const int nbins = N * RELS;                 // 400000
  const int Mpad = ((N + 127) / 128) * 128;   // 50048
  const int nsb = (nbins + SCAN_CHUNK - 1) / SCAN_CHUNK;  // scan1 blocks (391)

  char* base = (char*)d_ws;
  size_t off = 0;
  auto alloc = [&](size_t bytes) {
    void* r = base + off;
    off = (off + bytes + 511) & ~(size_t)511;
    return r;
  };
  unsigned short* Wt1  = (unsigned short*)alloc((size_t)256 * KDIM * 2);
  unsigned short* Wt2  = (unsigned short*)alloc((size_t)128 * KDIM * 2);
  int*            cnt  = (int*)alloc((size_t)nbins * 4);
  int*            strt = (int*)alloc((size_t)(nbins + 1) * 4);
  int*            bsum = (int*)alloc((size_t)(nsb + 1) * 4);
  int*            ssrc = (int*)alloc((size_t)E * 4);
  unsigned short* A    = (unsigned short*)alloc((size_t)Mpad * KDIM * 2);
  unsigned short* h    = (unsigned short*)alloc((size_t)Mpad * F * 2);
  (void)ws_size; (void)n_in; (void)out_size;

  hipMemsetAsync(cnt, 0, (size_t)nbins * 4, stream);
  k_wt<<<(256 * KDIM + 255) / 256, 256, 0, stream>>>(W1, root1, Wt1, 256);
  k_wt<<<(128 * KDIM + 255) / 256, 256, 0, stream>>>(W2, root2, Wt2, 128);
  k_count<<<(E + 255) / 256, 256, 0, stream>>>(ei, et, cnt, E);
  k_scan1<<<nsb, 256, 0, stream>>>(cnt, strt, bsum, nbins);
  k_scan2<<<1, 1024, 0, stream>>>(bsum, nsb);
  k_scan3<<<(nbins + 255) / 256, 256, 0, stream>>>(strt, bsum, nbins, nsb);
  hipMemsetAsync(cnt, 0, (size_t)nbins * 4, stream);  // reuse as cursor
  k_scatter<<<(E + 255) / 256, 256, 0, stream>>>(ei, et, strt, cnt, ssrc, E);

  // Layer 1: bf16 self-features go into A's last 256 cols first, then the
  // aggregation gathers from that region (stride KDIM) -> half the gather bytes
  // vs fp32 x. No race: agg reads cols [2048,2304), writes cols [0,2048).
  k_copy_x<<<(N * 64 + 255) / 256, 256, 0, stream>>>(x, A, N);
  k_agg<<<(nbins + 3) / 4, 256, 0, stream>>>(A + 2048, KDIM, strt, ssrc, A, nbins);
  k_gemm<true, true><<<dim3(Mpad / 128, 2), 256, 0, stream>>>(A, Wt1, b1, h, 256, N);

  // Layer 2
  k_copy_h<<<(N * 64 + 255) / 256, 256, 0, stream>>>(h, A, N);
  k_agg<<<(nbins + 3) / 4, 256, 0, stream>>>(h, F, strt, ssrc, A, nbins);
  k_gemm<false, false><<<dim3(Mpad / 128, 1), 256, 0, stream>>>(A, Wt2, b2, d_out, 128, N);
}